// Round 5
// baseline (245.005 us; speedup 1.0000x reference)
//
#include <hip/hip_runtime.h>

// Integrate-and-fire SNN forward (IF_88957362634870).
// x: 8 frames of N = 4,194,304 fp32 (16 MiB each); out: 8 frames.
// Elementwise recurrence. Traffic floor ~196 MB (65 MB HBM fetch w/ L3
// residency + 131 MB NT write) -> ~31 us at 6.3 TB/s.
//
// R3/R4 finding: compiler sinks the frame loads to their uses no matter
// what (VGPR=36 despite 16 "live" fvec4 + sched_barrier) -> ~1 load in
// flight per wave -> latency-bound at 2.3 TB/s.
// R5 fix: one asm volatile block issues all 8 global_load_dwordx4 and the
// s_waitcnt vmcnt(0). The compiler cannot reorder or sink inside asm, so
// 8 KB/wave is guaranteed in flight (need ~9 KB/CU for 6.3 TB/s).

#define T1 8
#define T2 8
#define L_DIV 8.0f
#define EPS_C (-8e-05f)

typedef float fvec4 __attribute__((ext_vector_type(4)));

__global__ __launch_bounds__(256) void if_fwd_kernel(
    const fvec4* __restrict__ x,
    const float* __restrict__ thresh,
    fvec4* __restrict__ out,
    int n4)   // N/4 groups per frame
{
    const int i = blockIdx.x * blockDim.x + threadIdx.x;

    const float thre = thresh[0] / L_DIV;

    const fvec4* a0 = &x[(size_t)0 * n4 + i];
    const fvec4* a1 = &x[(size_t)1 * n4 + i];
    const fvec4* a2 = &x[(size_t)2 * n4 + i];
    const fvec4* a3 = &x[(size_t)3 * n4 + i];
    const fvec4* a4 = &x[(size_t)4 * n4 + i];
    const fvec4* a5 = &x[(size_t)5 * n4 + i];
    const fvec4* a6 = &x[(size_t)6 * n4 + i];
    const fvec4* a7 = &x[(size_t)7 * n4 + i];

    fvec4 xv[T1];
    // All 8 loads + the waitcnt in ONE asm block: un-sinkable, un-splittable.
    asm volatile(
        "global_load_dwordx4 %0, %8, off\n\t"
        "global_load_dwordx4 %1, %9, off\n\t"
        "global_load_dwordx4 %2, %10, off\n\t"
        "global_load_dwordx4 %3, %11, off\n\t"
        "global_load_dwordx4 %4, %12, off\n\t"
        "global_load_dwordx4 %5, %13, off\n\t"
        "global_load_dwordx4 %6, %14, off\n\t"
        "global_load_dwordx4 %7, %15, off\n\t"
        "s_waitcnt vmcnt(0)"
        : "=&v"(xv[0]), "=&v"(xv[1]), "=&v"(xv[2]), "=&v"(xv[3]),
          "=&v"(xv[4]), "=&v"(xv[5]), "=&v"(xv[6]), "=&v"(xv[7])
        : "v"(a0), "v"(a1), "v"(a2), "v"(a3),
          "v"(a4), "v"(a5), "v"(a6), "v"(a7)
        : "memory");

    float m[4], sc[4];
    #pragma unroll
    for (int k = 0; k < 4; ++k) { m[k] = 0.5f * thre; sc[k] = 0.0f; }

    // Phase 1: integrate T1 frames, fire-and-subtract.
    #pragma unroll
    for (int t = 0; t < T1; ++t) {
        #pragma unroll
        for (int k = 0; k < 4; ++k) {
            m[k] += xv[t][k];
            const float spike = (m[k] - thre >= EPS_C) ? thre : 0.0f;
            m[k] -= spike;
            sc[k] += spike;
        }
    }

    // Phase 2: 7 relaxation steps with reverse spikes (register-only).
    #pragma unroll
    for (int t = 0; t < T1 - 1; ++t) {
        #pragma unroll
        for (int k = 0; k < 4; ++k) {
            const float spike = (m[k] - thre >= EPS_C) ? thre : 0.0f;
            const float rev   = (-m[k] > 0.0f) ? thre : 0.0f;
            m[k] = m[k] - spike + rev;
            sc[k] += spike - rev;
        }
    }

    // Phase 3: emit T2 output frames (nontemporal: never re-read, keep L3
    // for the input).
    #pragma unroll
    for (int t = 0; t < T2; ++t) {
        fvec4 o;
        #pragma unroll
        for (int k = 0; k < 4; ++k) {
            const float spike = (sc[k] - thre >= EPS_C) ? thre : 0.0f;
            o[k] = spike;
            sc[k] -= spike;
        }
        __builtin_nontemporal_store(o, &out[(size_t)t * n4 + i]);
    }
}

extern "C" void kernel_launch(void* const* d_in, const int* in_sizes, int n_in,
                              void* d_out, int out_size, void* d_ws, size_t ws_size,
                              hipStream_t stream) {
    const fvec4* x      = (const fvec4*)d_in[0];
    const float* thresh = (const float*)d_in[1];
    fvec4*       out    = (fvec4*)d_out;

    const int N  = in_sizes[0] / T1;  // 4,194,304
    const int n4 = N / 4;             // 1,048,576

    const int block = 256;
    const int grid  = n4 / block;     // 4096, exact
    if_fwd_kernel<<<grid, block, 0, stream>>>(x, thresh, out, n4);
}